// Round 1
// baseline (513.113 us; speedup 1.0000x reference)
//
#include <hip/hip_runtime.h>
#include <hip/hip_bf16.h>

// BaseQVLayer: xp = x@Wx+bx; yp = y@Wy+by; At[j,i] = 2*(yp_j . xp_i)/(||xp_i||^2+||yp_j||^2);
// gwf = At@xp; out = relu(gwf@Wg+bg).  All GEMMs in bf16 MFMA (16x16x32), fp32 accum.
//
// Workspace layout (needs ~163 MB):
//   At   [8192*8192] bf16   (128 MB)
//   xpb  [8192* 512] bf16
//   ypb  [8192* 512] bf16
//   xpT  [ 512*8192] bf16
//   gwfb [8192* 512] bf16
//   WxT  [ 512*1024] bf16
//   WyT  [ 512*1024] bf16
//   WgT  [ 512* 512] bf16
//   Dx   [8192] f32, Dy [8192] f32 (contiguous, memset to 0)

typedef __attribute__((ext_vector_type(8))) short bf16x8;
typedef __attribute__((ext_vector_type(4))) short bf16x4;
typedef __attribute__((ext_vector_type(4))) float f32x4;

__device__ inline short f2b(float f) {
    // round-to-nearest-even f32 -> bf16 (inputs finite; NaN not expected)
    unsigned int u = __builtin_bit_cast(unsigned int, f);
    unsigned int r = (u + 0x7fffu + ((u >> 16) & 1u)) >> 16;
    return (short)r;
}

constexpr int EPI_XP  = 0;  // store bf16 xp, add bias, atomic row-norm accumulate
constexpr int EPI_AT  = 1;  // scale 2/(Dcol[n]+Drow[m]), store bf16
constexpr int EPI_GWF = 2;  // store bf16
constexpr int EPI_OUT = 3;  // bias + relu, store f32

// C = A @ B, with B given transposed (Bt[n][k]). 128x128 block tile, 256 threads,
// 4 waves each computing 64x64 via 4x4 of 16x16x32 MFMA. LDS tiles 128x32,
// row stride padded to 48 elems (96 B) for 16B-aligned b128 access.
template<int EPI, bool AF32>
__global__ __launch_bounds__(256)
void gemm_bt(const void* __restrict__ Aptr, int lda,
             const short* __restrict__ Bt, int ldb,
             int M, int N, int K,
             const float* __restrict__ bias,
             short* __restrict__ outb,
             float* __restrict__ outf,
             float* __restrict__ Dacc,
             const float* __restrict__ Drow,
             const float* __restrict__ Dcol)
{
    __shared__ short As[128 * 48];
    __shared__ short Bs[128 * 48];

    const int tid  = threadIdx.x;
    const int wave = tid >> 6;
    const int lane = tid & 63;
    const int quad = lane >> 4;
    const int l15  = lane & 15;
    const int wm   = (wave >> 1) * 64;
    const int wn   = (wave & 1) * 64;
    const int bm   = blockIdx.y * 128;
    const int bn   = blockIdx.x * 128;

    f32x4 acc[4][4];
#pragma unroll
    for (int i = 0; i < 4; i++)
#pragma unroll
        for (int j = 0; j < 4; j++)
            acc[i][j] = f32x4{0.f, 0.f, 0.f, 0.f};

    for (int k0 = 0; k0 < K; k0 += 32) {
        if (AF32) {
            const float* Af = (const float*)Aptr;
#pragma unroll
            for (int s = 0; s < 4; s++) {
                int seg = tid + 256 * s;          // 1024 segs: 128 rows x 8 float4
                int row = seg >> 3, c4 = seg & 7;
                const float4 v = *(const float4*)&Af[(size_t)(bm + row) * lda + k0 + c4 * 4];
                bf16x4 b;
                b[0] = f2b(v.x); b[1] = f2b(v.y); b[2] = f2b(v.z); b[3] = f2b(v.w);
                *(bf16x4*)&As[row * 48 + c4 * 4] = b;
            }
        } else {
            const short* Ab = (const short*)Aptr;
#pragma unroll
            for (int s = 0; s < 2; s++) {
                int seg = tid + 256 * s;          // 512 segs: 128 rows x 4 bf16x8
                int row = seg >> 2, c8 = seg & 3;
                *(bf16x8*)&As[row * 48 + c8 * 8] =
                    *(const bf16x8*)&Ab[(size_t)(bm + row) * lda + k0 + c8 * 8];
            }
        }
#pragma unroll
        for (int s = 0; s < 2; s++) {
            int seg = tid + 256 * s;
            int row = seg >> 2, c8 = seg & 3;
            *(bf16x8*)&Bs[row * 48 + c8 * 8] =
                *(const bf16x8*)&Bt[(size_t)(bn + row) * ldb + k0 + c8 * 8];
        }
        __syncthreads();

        bf16x8 af[4], bfr[4];
#pragma unroll
        for (int i = 0; i < 4; i++)
            af[i] = *(const bf16x8*)&As[(wm + i * 16 + l15) * 48 + quad * 8];
#pragma unroll
        for (int j = 0; j < 4; j++)
            bfr[j] = *(const bf16x8*)&Bs[(wn + j * 16 + l15) * 48 + quad * 8];
#pragma unroll
        for (int i = 0; i < 4; i++)
#pragma unroll
            for (int j = 0; j < 4; j++)
                acc[i][j] = __builtin_amdgcn_mfma_f32_16x16x32_bf16(af[i], bfr[j], acc[i][j], 0, 0, 0);
        __syncthreads();
    }

    // Epilogue. C/D layout: col = lane&15, row = quad*4 + r  [verified m89/m91]
#pragma unroll
    for (int im = 0; im < 4; im++) {
#pragma unroll
        for (int r = 0; r < 4; r++) {
            const int gm = bm + wm + im * 16 + quad * 4 + r;
            if (EPI == EPI_XP) {
                float s = 0.f;
#pragma unroll
                for (int jn = 0; jn < 4; jn++) {
                    const int gn = bn + wn + jn * 16 + l15;
                    float v = acc[im][jn][r] + bias[gn];
                    outb[(size_t)gm * N + gn] = f2b(v);
                    s += v * v;
                }
#pragma unroll
                for (int m = 1; m < 16; m <<= 1) s += __shfl_xor(s, m, 64);
                if (l15 == 0) atomicAdd(&Dacc[gm], s);
            } else if (EPI == EPI_AT) {
                const float dy = Drow[gm];
#pragma unroll
                for (int jn = 0; jn < 4; jn++) {
                    const int gn = bn + wn + jn * 16 + l15;
                    float v = 2.f * acc[im][jn][r] / (Dcol[gn] + dy);
                    outb[(size_t)gm * N + gn] = f2b(v);
                }
            } else if (EPI == EPI_GWF) {
#pragma unroll
                for (int jn = 0; jn < 4; jn++) {
                    const int gn = bn + wn + jn * 16 + l15;
                    outb[(size_t)gm * N + gn] = f2b(acc[im][jn][r]);
                }
            } else {
#pragma unroll
                for (int jn = 0; jn < 4; jn++) {
                    const int gn = bn + wn + jn * 16 + l15;
                    float v = acc[im][jn][r] + bias[gn];
                    outf[(size_t)gm * N + gn] = fmaxf(v, 0.f);
                }
            }
        }
    }
}

// 32x32 LDS-tiled transpose, f32 in -> bf16 out.  in[R][C] -> out[C][R]
__global__ __launch_bounds__(256)
void transpose_f32_bf16(const float* __restrict__ in, short* __restrict__ out, int R, int C)
{
    __shared__ short t[32][33];
    const int tx = threadIdx.x, ty = threadIdx.y;
    const int bx = blockIdx.x * 32, by = blockIdx.y * 32;
#pragma unroll
    for (int i = 0; i < 32; i += 8)
        t[ty + i][tx] = f2b(in[(size_t)(by + ty + i) * C + bx + tx]);
    __syncthreads();
#pragma unroll
    for (int i = 0; i < 32; i += 8)
        out[(size_t)(bx + ty + i) * R + by + tx] = t[tx][ty + i];
}

// bf16 in -> bf16 out transpose
__global__ __launch_bounds__(256)
void transpose_bf16(const short* __restrict__ in, short* __restrict__ out, int R, int C)
{
    __shared__ short t[32][33];
    const int tx = threadIdx.x, ty = threadIdx.y;
    const int bx = blockIdx.x * 32, by = blockIdx.y * 32;
#pragma unroll
    for (int i = 0; i < 32; i += 8)
        t[ty + i][tx] = in[(size_t)(by + ty + i) * C + bx + tx];
    __syncthreads();
#pragma unroll
    for (int i = 0; i < 32; i += 8)
        out[(size_t)(bx + ty + i) * R + by + tx] = t[tx][ty + i];
}

extern "C" void kernel_launch(void* const* d_in, const int* in_sizes, int n_in,
                              void* d_out, int out_size, void* d_ws, size_t ws_size,
                              hipStream_t stream)
{
    const float* x  = (const float*)d_in[0];   // [8192,1024]
    const float* y  = (const float*)d_in[1];   // [8192,1024]
    const float* Wx = (const float*)d_in[2];   // [1024, 512]
    const float* bx = (const float*)d_in[3];   // [512]
    const float* Wy = (const float*)d_in[4];   // [1024, 512]
    const float* by = (const float*)d_in[5];   // [512]
    const float* Wg = (const float*)d_in[6];   // [512, 512]
    const float* bg = (const float*)d_in[7];   // [512]
    float* out = (float*)d_out;                // [8192, 512] f32

    char* p = (char*)d_ws;
    short* At   = (short*)p; p += (size_t)8192 * 8192 * 2;
    short* xpb  = (short*)p; p += (size_t)8192 * 512 * 2;
    short* ypb  = (short*)p; p += (size_t)8192 * 512 * 2;
    short* xpT  = (short*)p; p += (size_t)512 * 8192 * 2;
    short* gwfb = (short*)p; p += (size_t)8192 * 512 * 2;
    short* WxT  = (short*)p; p += (size_t)512 * 1024 * 2;
    short* WyT  = (short*)p; p += (size_t)512 * 1024 * 2;
    short* WgT  = (short*)p; p += (size_t)512 * 512 * 2;
    float* Dx   = (float*)p; p += (size_t)8192 * 4;
    float* Dy   = (float*)p; p += (size_t)8192 * 4;

    hipMemsetAsync(Dx, 0, 2 * 8192 * sizeof(float), stream);  // Dx and Dy contiguous

    dim3 tb(32, 8);
    transpose_f32_bf16<<<dim3(512 / 32, 1024 / 32), tb, 0, stream>>>(Wx, WxT, 1024, 512);
    transpose_f32_bf16<<<dim3(512 / 32, 1024 / 32), tb, 0, stream>>>(Wy, WyT, 1024, 512);
    transpose_f32_bf16<<<dim3(512 / 32, 512 / 32),  tb, 0, stream>>>(Wg, WgT, 512, 512);

    // G1: xp = x@Wx + bx   [8192,512], also Dx row norms
    gemm_bt<EPI_XP, true><<<dim3(512 / 128, 8192 / 128), 256, 0, stream>>>(
        x, 1024, WxT, 1024, 8192, 512, 1024, bx, xpb, nullptr, Dx, nullptr, nullptr);
    // G2: yp = y@Wy + by   [8192,512], also Dy row norms
    gemm_bt<EPI_XP, true><<<dim3(512 / 128, 8192 / 128), 256, 0, stream>>>(
        y, 1024, WyT, 1024, 8192, 512, 1024, by, ypb, nullptr, Dy, nullptr, nullptr);

    // xpT for G4's Bt operand
    transpose_bf16<<<dim3(512 / 32, 8192 / 32), tb, 0, stream>>>(xpb, xpT, 8192, 512);

    // G3: At[j,i] = 2*(yp_j . xp_i)/(Dx[i] + Dy[j])   [8192(j), 8192(i)] bf16
    gemm_bt<EPI_AT, false><<<dim3(8192 / 128, 8192 / 128), 256, 0, stream>>>(
        ypb, 512, xpb, 512, 8192, 8192, 512, nullptr, At, nullptr, nullptr, Dy, Dx);

    // G4: gwf = At @ xp    [8192, 512] bf16   (Bt = xpT)
    gemm_bt<EPI_GWF, false><<<dim3(512 / 128, 8192 / 128), 256, 0, stream>>>(
        At, 8192, xpT, 8192, 8192, 512, 8192, nullptr, gwfb, nullptr, nullptr, nullptr, nullptr);

    // G5: out = relu(gwf @ Wg + bg)   [8192, 512] f32
    gemm_bt<EPI_OUT, false><<<dim3(512 / 128, 8192 / 128), 256, 0, stream>>>(
        gwfb, 512, WgT, 512, 8192, 512, 512, bg, nullptr, out, nullptr, nullptr, nullptr);
}